// Round 1
// baseline (74.161 us; speedup 1.0000x reference)
//
#include <hip/hip_runtime.h>
#include <math.h>

#define NB   32
#define SEQ  2048
#define HD   1024
#define CDIM 256
#define VOC  64

// ---------------- split-K tiled GEMM: out_part[ks][b][n] = sum_{k in ks-range} X[b,k]*W[n,k]
// MODE 0: LSTM   X = [emb(char) | h_prev] (K=1280), W = [w_ih | w_hh] (N=4096), KSPLIT=4 (KRANGE=320)
// MODE 1: concat X = xcat2 (K=2048),            W = concat_w (N=1024), KSPLIT=8 (KRANGE=256)
template<int MODE>
__global__ void __launch_bounds__(256) gemm_splitk(
    const float* __restrict__ XA, const int* __restrict__ chars,
    const float* __restrict__ XB,
    const float* __restrict__ WA, const float* __restrict__ WB,
    float* __restrict__ out_part)
{
    const int N      = (MODE == 0) ? 4096 : 1024;
    const int KRANGE = (MODE == 0) ? 320  : 256;
    const int n0    = blockIdx.x * 16;
    const int kbase = blockIdx.y * KRANGE;

    __shared__ float Xs[32][33];
    __shared__ float Ws[32][17];

    const int t  = threadIdx.x;
    const int nn = t & 15, bb = t >> 4;   // nn: 0..15, bb: 0..15 (handles bb and bb+16)
    float acc0 = 0.f, acc1 = 0.f;

    for (int k0 = kbase; k0 < kbase + KRANGE; k0 += 32) {
        {   // X tile: [32 b][32 k] -> Xs[k][b]
            int b = t >> 3, kk = (t & 7) * 4;
            float4 xv;
            if (MODE == 0) {
                int k = k0 + kk;
                if (k < CDIM) xv = *(const float4*)(XA + chars[b] * CDIM + k);
                else          xv = *(const float4*)(XB + b * HD + (k - CDIM));
            } else {
                xv = *(const float4*)(XA + b * 2048 + k0 + kk);
            }
            Xs[kk + 0][b] = xv.x; Xs[kk + 1][b] = xv.y;
            Xs[kk + 2][b] = xv.z; Xs[kk + 3][b] = xv.w;
        }
        {   // W tile: [16 n][32 k] -> Ws[k][n]
            int nl = t >> 4, kk = (t & 15) * 2;
            int n = n0 + nl;
            float2 wv;
            if (MODE == 0) {
                int k = k0 + kk;
                if (k < CDIM) wv = *(const float2*)(WA + n * CDIM + k);
                else          wv = *(const float2*)(WB + n * HD + (k - CDIM));
            } else {
                wv = *(const float2*)(WA + n * 2048 + k0 + kk);
            }
            Ws[kk + 0][nl] = wv.x; Ws[kk + 1][nl] = wv.y;
        }
        __syncthreads();
        #pragma unroll
        for (int k = 0; k < 32; ++k) {
            float wv = Ws[k][nn];
            acc0 += wv * Xs[k][bb];
            acc1 += wv * Xs[k][bb + 16];
        }
        __syncthreads();
    }
    out_part[(size_t)(blockIdx.y * 32 + bb     ) * N + n0 + nn] = acc0;
    out_part[(size_t)(blockIdx.y * 32 + bb + 16) * N + n0 + nn] = acc1;
}

// ---------------- LSTM gate epilogue: sum split-K partials + biases, compute c_new/h_new
__global__ void lstm_gates(const float* __restrict__ zpart,
                           const float* __restrict__ b_ih, const float* __restrict__ b_hh,
                           const float* __restrict__ c_prev,
                           float* __restrict__ d_out, float* __restrict__ xcat2)
{
    int idx = blockIdx.x * 256 + threadIdx.x;   // 32*1024
    int b = idx >> 10, j = idx & 1023;
    float z[4];
    #pragma unroll
    for (int g = 0; g < 4; ++g) {
        int n = g * 1024 + j;
        float v = b_ih[n] + b_hh[n];
        #pragma unroll
        for (int s = 0; s < 4; ++s) v += zpart[(size_t)(s * 32 + b) * 4096 + n];
        z[g] = v;
    }
    float gi = 1.f / (1.f + expf(-z[0]));
    float gf = 1.f / (1.f + expf(-z[1]));
    float gg = tanhf(z[2]);
    float go = 1.f / (1.f + expf(-z[3]));
    float c = gf * c_prev[idx] + gi * gg;
    float h = go * tanhf(c);
    d_out[2048 + idx]         = h;   // h_new
    d_out[2048 + 32768 + idx] = c;   // c_new
    xcat2[b * 2048 + 1024 + j] = h;
}

// ---------------- one-pass flash attention partials (softmax is h_new-independent: constant shift)
__global__ void __launch_bounds__(256) attn_flash(
    const float* __restrict__ enc, const int* __restrict__ lens,
    const float* __restrict__ attn_w, float* __restrict__ part)
{
    int b = blockIdx.x >> 5, chunk = blockIdx.x & 31;
    int t = threadIdx.x, w = t >> 6, lane = t & 63;
    int len = lens[b];
    int sbeg = chunk * 64 + w * 16;

    float4 we[4], ctx[4];
    #pragma unroll
    for (int i = 0; i < 4; ++i) {
        we[i]  = *(const float4*)(attn_w + i * 256 + lane * 4);   // w_enc slice
        ctx[i] = make_float4(0.f, 0.f, 0.f, 0.f);
    }
    float m = -1e30f, l = 0.f;
    const float* ebase = enc + (size_t)b * SEQ * HD;
    for (int ss = 0; ss < 16; ++ss) {
        int s = sbeg + ss;
        if (s >= len) break;                       // wave-uniform
        float4 e[4];
        const float* ep = ebase + (size_t)s * HD + lane * 4;
        #pragma unroll
        for (int i = 0; i < 4; ++i) e[i] = *(const float4*)(ep + i * 256);
        float v = 0.f;
        #pragma unroll
        for (int i = 0; i < 4; ++i)
            v += e[i].x * we[i].x + e[i].y * we[i].y + e[i].z * we[i].z + e[i].w * we[i].w;
        #pragma unroll
        for (int off = 32; off > 0; off >>= 1) v += __shfl_xor(v, off, 64);
        if (v > m) {                               // online softmax rescale (wave-uniform)
            float beta = __expf(m - v);
            l *= beta;
            #pragma unroll
            for (int i = 0; i < 4; ++i) {
                ctx[i].x *= beta; ctx[i].y *= beta; ctx[i].z *= beta; ctx[i].w *= beta;
            }
            m = v;
        }
        float p = __expf(v - m);
        l += p;
        #pragma unroll
        for (int i = 0; i < 4; ++i) {
            ctx[i].x += p * e[i].x; ctx[i].y += p * e[i].y;
            ctx[i].z += p * e[i].z; ctx[i].w += p * e[i].w;
        }
    }
    // combine the block's 4 waves
    __shared__ float ctxs[4][1024];
    __shared__ float wm[4], wl[4];
    #pragma unroll
    for (int i = 0; i < 4; ++i)
        *(float4*)&ctxs[w][i * 256 + lane * 4] = ctx[i];
    if (lane == 0) { wm[w] = m; wl[w] = l; }
    __syncthreads();
    float mb = fmaxf(fmaxf(wm[0], wm[1]), fmaxf(wm[2], wm[3]));
    float f0 = __expf(wm[0] - mb), f1 = __expf(wm[1] - mb);
    float f2 = __expf(wm[2] - mb), f3 = __expf(wm[3] - mb);
    float lb = f0 * wl[0] + f1 * wl[1] + f2 * wl[2] + f3 * wl[3];
    float* rec = part + (size_t)blockIdx.x * 1032;
    #pragma unroll
    for (int i = 0; i < 4; ++i) {
        int hh = t + i * 256;
        rec[hh] = f0 * ctxs[0][hh] + f1 * ctxs[1][hh] + f2 * ctxs[2][hh] + f3 * ctxs[3][hh];
    }
    if (t == 0) { rec[1024] = mb; rec[1025] = lb; }
}

// ---------------- combine 32 chunk-partials per batch row -> context, into xcat2[:, 0:1024]
__global__ void attn_combine(const float* __restrict__ part, float* __restrict__ xcat2)
{
    int b = blockIdx.x >> 2, slice = blockIdx.x & 3;
    int t = threadIdx.x;
    __shared__ float sm[32], sl[32];
    if (t < 32) {
        const float* rec = part + (size_t)(b * 32 + t) * 1032;
        sm[t] = rec[1024]; sl[t] = rec[1025];
    }
    __syncthreads();
    float mg = -1e30f;
    #pragma unroll
    for (int i = 0; i < 32; ++i) mg = fmaxf(mg, sm[i]);
    float L = 0.f;
    #pragma unroll
    for (int i = 0; i < 32; ++i) L += __expf(sm[i] - mg) * sl[i];
    int hh = slice * 256 + t;
    float acc = 0.f;
    for (int i = 0; i < 32; ++i)
        acc += __expf(sm[i] - mg) * part[(size_t)(b * 32 + i) * 1032 + hh];
    xcat2[b * 2048 + hh] = acc / L;
}

// ---------------- nh = tanh(sum split-K partials + concat_b)
__global__ void nh_reduce(const float* __restrict__ nhpart,
                          const float* __restrict__ concat_b, float* __restrict__ nh)
{
    int idx = blockIdx.x * 256 + threadIdx.x;   // 32*1024
    int b = idx >> 10, n = idx & 1023;
    float v = concat_b[n];
    #pragma unroll
    for (int s = 0; s < 8; ++s) v += nhpart[(size_t)(s * 32 + b) * 1024 + n];
    nh[idx] = tanhf(v);
}

// ---------------- output projection: one wave per (b, v) dot of length 1024
__global__ void out_proj(const float* __restrict__ nh, const float* __restrict__ out_w,
                         const float* __restrict__ out_b, float* __restrict__ d_out)
{
    int wid  = blockIdx.x * 4 + (threadIdx.x >> 6);  // 0..2047
    int lane = threadIdx.x & 63;
    int b = wid >> 6, v = wid & 63;
    const float* wr = out_w + v * 1024 + lane * 4;
    const float* nr = nh    + b * 1024 + lane * 4;
    float acc = 0.f;
    #pragma unroll
    for (int i = 0; i < 4; ++i) {
        float4 wv = *(const float4*)(wr + i * 256);
        float4 nv = *(const float4*)(nr + i * 256);
        acc += wv.x * nv.x + wv.y * nv.y + wv.z * nv.z + wv.w * nv.w;
    }
    #pragma unroll
    for (int off = 32; off > 0; off >>= 1) acc += __shfl_xor(acc, off, 64);
    if (lane == 0) d_out[b * 64 + v] = acc + out_b[v];
}

extern "C" void kernel_launch(void* const* d_in, const int* in_sizes, int n_in,
                              void* d_out, int out_size, void* d_ws, size_t ws_size,
                              hipStream_t stream)
{
    const int*   chars    = (const int*)  d_in[0];
    const float* h_prev   = (const float*)d_in[1];
    const float* c_prev   = (const float*)d_in[2];
    const int*   lens     = (const int*)  d_in[3];
    const float* enc      = (const float*)d_in[4];
    const float* emb      = (const float*)d_in[5];
    const float* w_ih     = (const float*)d_in[6];
    const float* w_hh     = (const float*)d_in[7];
    const float* b_ih     = (const float*)d_in[8];
    const float* b_hh     = (const float*)d_in[9];
    const float* attn_w   = (const float*)d_in[10];
    const float* concat_w = (const float*)d_in[12];
    const float* concat_b = (const float*)d_in[13];
    const float* out_w    = (const float*)d_in[14];
    const float* out_b    = (const float*)d_in[15];
    float* out = (float*)d_out;

    float* ws = (float*)d_ws;
    float* zpart  = ws;                      // 4*32*4096   = 524288
    float* xcat2  = zpart + 524288;          // 32*2048     = 65536
    float* part   = xcat2 + 65536;           // 1024*1032   = 1056768
    float* nhpart = part + 1056768;          // 8*32*1024   = 262144
    float* nh     = nhpart + 262144;         // 32*1024     = 32768

    // attention (independent of LSTM state — softmax shift-invariance)
    attn_flash<<<dim3(1024), 256, 0, stream>>>(enc, lens, attn_w, part);
    // LSTM cell
    gemm_splitk<0><<<dim3(256, 4), 256, 0, stream>>>(emb, chars, h_prev, w_ih, w_hh, zpart);
    lstm_gates<<<dim3(128), 256, 0, stream>>>(zpart, b_ih, b_hh, c_prev, out, xcat2);
    // context
    attn_combine<<<dim3(128), 256, 0, stream>>>(part, xcat2);
    // concat projection + tanh
    gemm_splitk<1><<<dim3(64, 8), 256, 0, stream>>>(xcat2, nullptr, nullptr, concat_w, nullptr, nhpart);
    nh_reduce<<<dim3(128), 256, 0, stream>>>(nhpart, concat_b, nh);
    // vocab projection
    out_proj<<<dim3(512), 256, 0, stream>>>(nh, out_w, out_b, out);
}